// Round 13
// baseline (324.725 us; speedup 1.0000x reference)
//
#include <hip/hip_runtime.h>
#include <math.h>

#define DI 1536
#define DM 768
#define NSTATE 16
#define DTRANK 48
#define LSEQ 1024
#define NBATCH 2
#define MROWS (NBATCH*LSEQ)   // 2048
#define NXR 3072              // 2*DI
#define NCHUNK 128
#define CLEN 8
#define SCB 128               // scan channels per block
#define DMP 16                // delta rows per block
#define ULDS 1544             // padded u-LDS row stride (bf16)

typedef __attribute__((ext_vector_type(4))) float f32x4;
typedef __attribute__((ext_vector_type(8))) short s16x8;
typedef __attribute__((ext_vector_type(4))) unsigned int u32x4;

__device__ __forceinline__ unsigned short f2bf(float f) {
  unsigned int x = __builtin_bit_cast(unsigned int, f);
  return (unsigned short)((x + 0x7fffu + ((x >> 16) & 1u)) >> 16);
}
__device__ __forceinline__ float bf2f(unsigned short b) {
  unsigned int u = ((unsigned int)b) << 16;
  return __builtin_bit_cast(float, u);
}

__device__ __forceinline__ void gload_lds16(const void* g, void* l) {
  __builtin_amdgcn_global_load_lds(
      (const __attribute__((address_space(1))) void*)g,
      (__attribute__((address_space(3))) void*)l, 16, 0, 0);
}

// ---------------- merged prep ----------------
// [0,768) x->bf16 | [768,3072) W_in^T | [3072,4224) W_out^T | [4224,4368) W_x^T
// [4368,4416) negA[n][d] = -exp(A_log[d][n])
__global__ __launch_bounds__(256) void prep_kernel(
    const float* __restrict__ x, const float* __restrict__ W_in,
    const float* __restrict__ W_out, const float* __restrict__ W_x,
    const float* __restrict__ A_log,
    unsigned short* __restrict__ x_bf, unsigned short* __restrict__ WinT,
    unsigned short* __restrict__ WoutT, unsigned short* __restrict__ WxT,
    float* __restrict__ negA)
{
  __shared__ float t[32][33];
  const int bid = blockIdx.x;
  const int tid = threadIdx.x;
  if (bid < 768) {                       // x -> x_bf (8 elems/thread)
    long i = ((long)bid * 256 + tid) * 8;
    f32x4 v0 = *(const f32x4*)&x[i];
    f32x4 v1 = *(const f32x4*)&x[i + 4];
    unsigned short o[8];
    #pragma unroll
    for (int j = 0; j < 4; ++j) { o[j] = f2bf(v0[j]); o[4 + j] = f2bf(v1[j]); }
    *(u32x4*)&x_bf[i] = *(u32x4*)o;
    return;
  }
  int tx = tid & 31, ty = tid >> 5;
  if (bid >= 4368) {                     // A_log [DI][16] -> negA [16][DI]
    int rtile = (bid - 4368) * 32;
    #pragma unroll
    for (int i = 0; i < 4; ++i) {
      int r = ty + i * 8;
      if (tx < 16) t[r][tx] = A_log[(long)(rtile + r) * NSTATE + tx];
    }
    __syncthreads();
    #pragma unroll
    for (int i = 0; i < 2; ++i) {
      int cc = ty + i * 8;               // 0..15
      negA[(long)cc * DI + rtile + tx] = -__expf(t[tx][cc]);
    }
    return;
  }
  const float* in; unsigned short* out; int R, C, bx, by; bool guard = false;
  if (bid < 3072)      { int q = bid - 768;  in = W_in;  out = WinT;  R = DM; C = NXR; bx = q % 96; by = q / 96; }
  else if (bid < 4224) { int q = bid - 3072; in = W_out; out = WoutT; R = DI; C = DM;  bx = q % 24; by = q / 24; }
  else                 { int q = bid - 4224; in = W_x;   out = WxT;   R = DI; C = 80;  bx = q % 3;  by = q / 3; guard = true; }
  int ctile = bx * 32, rtile = by * 32;
  #pragma unroll
  for (int i = 0; i < 4; ++i) {
    int r = ty + i * 8;
    if (!guard || (rtile + r < R && ctile + tx < C))
      t[r][tx] = in[(long)(rtile + r) * C + ctile + tx];
  }
  __syncthreads();
  #pragma unroll
  for (int i = 0; i < 4; ++i) {
    int cc = ty + i * 8;
    if (!guard || (ctile + cc < C && rtile + tx < R))
      out[(long)(ctile + cc) * R + rtile + tx] = f2bf(t[tx][cc]);
  }
}

// ---------------- bf16 MFMA GEMM: C = A @ BT^T ----------------
// SPLIT=true (gemm1): cols < DI -> f32 xi[m][DI]; cols >= DI -> bf16 res_bf[m][DI]
template<int FM, int FN, bool SPLIT>
__global__ __launch_bounds__(256) void gemm_bf16(
    const unsigned short* __restrict__ A,
    const unsigned short* __restrict__ BT,
    float* __restrict__ C,               // SPLIT: xi buffer
    unsigned short* __restrict__ res_bf, // SPLIT only
    int M, int N, int K)
{
  constexpr int BM = 32 * FM, BN = 32 * FN;
  constexpr int TM = BM / 16, TN = BN / 16;
  __shared__ unsigned short Ap[BM * 32];
  __shared__ unsigned short Bp[BN * 32];
  const int tid = threadIdx.x;
  const int lane = tid & 63, wave = tid >> 6;
  const int wr = wave >> 1, wc = wave & 1;
  const int lg = lane >> 4, lr = lane & 15;
  const int m0 = blockIdx.y * BM, n0 = blockIdx.x * BN;
  f32x4 acc[FM][FN] = {};
  for (int k0 = 0; k0 < K; k0 += 32) {
    #pragma unroll
    for (int p = 0; p < TM / 4; ++p) {
      int tile = wave + p * 4;
      gload_lds16(&A[(long)(m0 + tile * 16 + lr) * K + k0 + lg * 8], &Ap[tile * 512]);
    }
    #pragma unroll
    for (int p = 0; p < TN / 4; ++p) {
      int tile = wave + p * 4;
      gload_lds16(&BT[(long)(n0 + tile * 16 + lr) * K + k0 + lg * 8], &Bp[tile * 512]);
    }
    __syncthreads();
    s16x8 af[FM], bfr[FN];
    #pragma unroll
    for (int m = 0; m < FM; ++m)
      af[m] = *(s16x8*)&Ap[(((wr * FM + m) * 4 + lg) * 16 + lr) * 8];
    #pragma unroll
    for (int n = 0; n < FN; ++n)
      bfr[n] = *(s16x8*)&Bp[(((wc * FN + n) * 4 + lg) * 16 + lr) * 8];
    #pragma unroll
    for (int m = 0; m < FM; ++m)
      #pragma unroll
      for (int n = 0; n < FN; ++n)
        acc[m][n] = __builtin_amdgcn_mfma_f32_16x16x32_bf16(af[m], bfr[n], acc[m][n], 0, 0, 0);
    __syncthreads();
  }
  #pragma unroll
  for (int m = 0; m < FM; ++m)
    #pragma unroll
    for (int n = 0; n < FN; ++n)
      #pragma unroll
      for (int r = 0; r < 4; ++r) {
        int row = m0 + wr * 16 * FM + m * 16 + lg * 4 + r;
        int col = n0 + wc * 16 * FN + n * 16 + lr;
        if (SPLIT) {
          if (n0 < DI) C[(long)row * DI + col] = acc[m][n][r];
          else res_bf[(long)row * DI + col - DI] = f2bf(acc[m][n][r]);
        } else {
          C[(long)row * N + col] = acc[m][n][r];
        }
      }
}

// ---------------- fused conv+silu + xdbl MFMA ----------------
// grid MROWS/16 = 128 blocks, 256 thr. Block owns rows m0..m0+15.
// Phase A: u = silu(conv(xi)) -> LDS (bf16, padded stride) + global u_bf.
// Phase B: xdbl = u @ WxT^T via MFMA, A-fragments from LDS.
__global__ __launch_bounds__(256) void mid_kernel(
    const float* __restrict__ xi,
    const float* __restrict__ conv_w,
    const float* __restrict__ conv_b,
    const unsigned short* __restrict__ WxT,
    unsigned short* __restrict__ u_bf,
    float* __restrict__ xdbl)
{
  __shared__ __align__(16) char smem[16 * ULDS * 2];   // 49408 B
  unsigned short* uL = (unsigned short*)smem;           // [16][ULDS] bf16
  float* red = (float*)smem;                            // [4][16][80] f32 (aliases uL after B reads)
  const int tid = threadIdx.x;
  const int m0 = blockIdx.x * 16;
  // ---- phase A: conv + bias + silu ----
  for (int i = tid; i < 16 * DI; i += 256) {
    int row = i / DI, col = i - row * DI;
    int m = m0 + row;
    int t = m % LSEQ;
    float w0 = conv_w[col * 4 + 0], w1 = conv_w[col * 4 + 1];
    float w2 = conv_w[col * 4 + 2], w3 = conv_w[col * 4 + 3];
    float acc = conv_b[col];
    if (t >= 3) acc = fmaf(xi[(long)(m - 3) * DI + col], w0, acc);
    if (t >= 2) acc = fmaf(xi[(long)(m - 2) * DI + col], w1, acc);
    if (t >= 1) acc = fmaf(xi[(long)(m - 1) * DI + col], w2, acc);
    acc = fmaf(xi[(long)m * DI + col], w3, acc);
    float s = acc / (1.f + __expf(-acc));
    unsigned short bv = f2bf(s);
    uL[row * ULDS + col] = bv;
    u_bf[(long)m * DI + col] = bv;
  }
  __syncthreads();
  // ---- phase B: MFMA, 4 waves split K ----
  const int lane = tid & 63, wave = tid >> 6;
  const int lg = lane >> 4, lr = lane & 15;
  f32x4 acc[5] = {};
  const int kbase = wave * (DI / 4);
  #pragma unroll
  for (int kk = 0; kk < DI / 4; kk += 32) {
    int k0 = kbase + kk;
    s16x8 af = *(const s16x8*)&uL[lr * ULDS + k0 + lg * 8];
    #pragma unroll
    for (int n = 0; n < 5; ++n) {
      s16x8 bfr = *(const s16x8*)&WxT[(long)(n * 16 + lr) * DI + k0 + lg * 8];
      acc[n] = __builtin_amdgcn_mfma_f32_16x16x32_bf16(af, bfr, acc[n], 0, 0, 0);
    }
  }
  __syncthreads();   // all uL reads done -> safe to overwrite with red
  #pragma unroll
  for (int n = 0; n < 5; ++n)
    #pragma unroll
    for (int r = 0; r < 4; ++r)
      red[(wave * 16 + lg * 4 + r) * 80 + n * 16 + lr] = acc[n][r];
  __syncthreads();
  for (int i = tid; i < 16 * 80; i += 256) {
    int row = i / 80, col = i - row * 80;
    float s = red[(0 * 16 + row) * 80 + col] + red[(1 * 16 + row) * 80 + col]
            + red[(2 * 16 + row) * 80 + col] + red[(3 * 16 + row) * 80 + col];
    xdbl[(long)(m0 + row) * 80 + col] = s;
  }
}

// ---------------- delta = softplus(xdbl[:, :48] @ W_dt + b_dt) ----------------
// 16 m-rows per block; f32x4 LDS reads (4x fewer LDS instructions).
__global__ __launch_bounds__(256) void delta_kernel(
    const float* __restrict__ xdbl,
    const float* __restrict__ W_dt,
    const float* __restrict__ b_dt,
    float* __restrict__ delta)
{
  __shared__ __align__(16) float sx[DMP][DTRANK];
  const int tid = threadIdx.x;
  const int c = blockIdx.x * 256 + tid;
  const int m0 = blockIdx.y * DMP;
  for (int i = tid; i < DMP * DTRANK; i += 256) {
    int mm = i / DTRANK, r = i % DTRANK;
    sx[mm][r] = xdbl[(long)(m0 + mm) * 80 + r];
  }
  __syncthreads();
  float bias = b_dt[c];
  float acc[DMP];
  #pragma unroll
  for (int mm = 0; mm < DMP; ++mm) acc[mm] = bias;
  for (int r = 0; r < DTRANK; r += 4) {
    float wv0 = W_dt[(long)(r + 0) * DI + c];
    float wv1 = W_dt[(long)(r + 1) * DI + c];
    float wv2 = W_dt[(long)(r + 2) * DI + c];
    float wv3 = W_dt[(long)(r + 3) * DI + c];
    #pragma unroll
    for (int mm = 0; mm < DMP; ++mm) {
      f32x4 s4 = *(const f32x4*)&sx[mm][r];
      float a = fmaf(s4[0], wv0, acc[mm]);
      a = fmaf(s4[1], wv1, a);
      a = fmaf(s4[2], wv2, a);
      acc[mm] = fmaf(s4[3], wv3, a);
    }
  }
  #pragma unroll
  for (int mm = 0; mm < DMP; ++mm) {
    float v = acc[mm];
    float sp = (v > 20.f) ? v : log1pf(__expf(v));
    delta[(long)(m0 + mm) * DI + c] = sp;
  }
}

// ---------------- scan phase 1: n-major state, coalesced stores ----------------
// grid (DI/SCB=12, NCHUNK=128, NBATCH), block SCB=128
__global__ __launch_bounds__(SCB) void scan_ph1(
    const float* __restrict__ delta,
    const float* __restrict__ xdbl,
    const unsigned short* __restrict__ u_bf,
    const float* __restrict__ negA,
    float* __restrict__ Aprod,
    float* __restrict__ Hend)
{
  const int b = blockIdx.z, chunk = blockIdx.y;
  const int tid = threadIdx.x;
  const int d = blockIdx.x * SCB + tid;
  const long mbase = (long)b * LSEQ + chunk * CLEN;
  __shared__ __align__(16) float sB[CLEN][NSTATE];
  for (int i = tid; i < CLEN * NSTATE; i += SCB) {
    int t = i >> 4, j = i & 15;
    sB[t][j] = xdbl[(mbase + t) * 80 + DTRANK + j];
  }
  __syncthreads();
  float a[NSTATE];
  #pragma unroll
  for (int n = 0; n < NSTATE; ++n)
    a[n] = negA[(long)n * DI + d];
  float h[NSTATE] = {};
  float Ap[NSTATE];
  #pragma unroll
  for (int n = 0; n < NSTATE; ++n) Ap[n] = 1.f;
  #pragma unroll
  for (int t = 0; t < CLEN; ++t) {
    long m = mbase + t;
    float dt = delta[m * DI + d];
    float uu = bf2f(u_bf[m * DI + d]);
    float dtu = dt * uu;
    #pragma unroll
    for (int q = 0; q < 4; ++q) {
      f32x4 b4 = *(const f32x4*)&sB[t][q * 4];
      #pragma unroll
      for (int j = 0; j < 4; ++j) {
        int n = q * 4 + j;
        float dA = __expf(dt * a[n]);
        Ap[n] *= dA;
        h[n] = fmaf(dA, h[n], dtu * b4[j]);
      }
    }
  }
  const long o = ((long)(b * NCHUNK + chunk) * NSTATE) * DI + d;
  #pragma unroll
  for (int n = 0; n < NSTATE; ++n) {
    Aprod[o + (long)n * DI] = Ap[n];
    Hend[o + (long)n * DI] = h[n];
  }
}

// ---------------- scan phase 2: prefix across chunks; Hend -> Hstart in place ----------------
__global__ __launch_bounds__(256) void scan_ph2(
    const float* __restrict__ Aprod,
    float* __restrict__ Hend)
{
  int idx = blockIdx.x * 256 + threadIdx.x;   // [0, 2*1536*16)
  int b = idx / (DI * NSTATE);
  int r = idx % (DI * NSTATE);
  long o = (long)b * NCHUNK * DI * NSTATE + r;
  const long stride = (long)DI * NSTATE;
  float h = 0.f;
  for (int c = 0; c < NCHUNK; ++c) {
    float Ap = Aprod[o + c * stride];
    float He = Hend[o + c * stride];
    Hend[o + c * stride] = h;
    h = fmaf(Ap, h, He);
  }
}

// ---------------- scan phase 3: replay + y + gate -> yg (bf16) ----------------
__global__ __launch_bounds__(SCB) void scan_ph3(
    const float* __restrict__ delta,
    const float* __restrict__ xdbl,
    const unsigned short* __restrict__ u_bf,
    const unsigned short* __restrict__ res_bf,
    const float* __restrict__ negA,
    const float* __restrict__ Dp,
    const float* __restrict__ Hstart,  // = Hend buffer after ph2
    unsigned short* __restrict__ yg)
{
  const int b = blockIdx.z, chunk = blockIdx.y;
  const int tid = threadIdx.x;
  const int d = blockIdx.x * SCB + tid;
  const long mbase = (long)b * LSEQ + chunk * CLEN;
  __shared__ __align__(16) float sB[CLEN][NSTATE], sC[CLEN][NSTATE];
  for (int i = tid; i < CLEN * NSTATE; i += SCB) {
    int t = i >> 4, j = i & 15;
    long mo = (mbase + t) * 80 + DTRANK + j;
    sB[t][j] = xdbl[mo];
    sC[t][j] = xdbl[mo + NSTATE];
  }
  __syncthreads();
  float a[NSTATE];
  #pragma unroll
  for (int n = 0; n < NSTATE; ++n)
    a[n] = negA[(long)n * DI + d];
  const float Dv = Dp[d];
  const long o = ((long)(b * NCHUNK + chunk) * NSTATE) * DI + d;
  float h[NSTATE];
  #pragma unroll
  for (int n = 0; n < NSTATE; ++n)
    h[n] = Hstart[o + (long)n * DI];
  #pragma unroll
  for (int t = 0; t < CLEN; ++t) {
    long m = mbase + t;
    float dt = delta[m * DI + d];
    float uu = bf2f(u_bf[m * DI + d]);
    float rr = bf2f(res_bf[m * DI + d]);
    float dtu = dt * uu;
    float p0 = 0.f, p1 = 0.f, p2 = 0.f, p3 = 0.f;
    #pragma unroll
    for (int q = 0; q < 4; ++q) {
      f32x4 b4 = *(const f32x4*)&sB[t][q * 4];
      float dA0 = __expf(dt * a[q*4+0]);
      float dA1 = __expf(dt * a[q*4+1]);
      float dA2 = __expf(dt * a[q*4+2]);
      float dA3 = __expf(dt * a[q*4+3]);
      h[q*4+0] = fmaf(dA0, h[q*4+0], dtu * b4[0]);
      h[q*4+1] = fmaf(dA1, h[q*4+1], dtu * b4[1]);
      h[q*4+2] = fmaf(dA2, h[q*4+2], dtu * b4[2]);
      h[q*4+3] = fmaf(dA3, h[q*4+3], dtu * b4[3]);
    }
    #pragma unroll
    for (int q = 0; q < 4; ++q) {
      f32x4 c4 = *(const f32x4*)&sC[t][q * 4];
      p0 = fmaf(h[q*4+0], c4[0], p0);
      p1 = fmaf(h[q*4+1], c4[1], p1);
      p2 = fmaf(h[q*4+2], c4[2], p2);
      p3 = fmaf(h[q*4+3], c4[3], p3);
    }
    float yv = (p0 + p1) + (p2 + p3) + uu * Dv;
    float gate = rr / (1.f + __expf(-rr));
    yg[m * DI + d] = f2bf(yv * gate);
  }
}

// ---------------- launch ----------------
extern "C" void kernel_launch(void* const* d_in, const int* in_sizes, int n_in,
                              void* d_out, int out_size, void* d_ws, size_t ws_size,
                              hipStream_t stream)
{
  const float* x      = (const float*)d_in[0];
  const float* W_in   = (const float*)d_in[1];
  const float* conv_w = (const float*)d_in[2];
  const float* conv_b = (const float*)d_in[3];
  const float* W_x    = (const float*)d_in[4];
  const float* W_dt   = (const float*)d_in[5];
  const float* b_dt   = (const float*)d_in[6];
  const float* A_log  = (const float*)d_in[7];
  const float* Dp     = (const float*)d_in[8];
  const float* W_out  = (const float*)d_in[9];
  float* out = (float*)d_out;

  char* p = (char*)d_ws;   // ws = 256 MiB
  float* xi     = (float*)(p + 0);            // 12582912
  unsigned short* res_bf = (unsigned short*)(p + 12582912);  // 6291456
  unsigned short* u_bf   = (unsigned short*)(p + 18874368);  // 6291456
  float* xdbl   = (float*)(p + 25165824);     // 655360
  float* delta  = (float*)(p + 25821184);     // 12582912
  float* Aprod  = (float*)(p + 38404096);     // 25165824 (NCHUNK=128)
  float* Hend   = (float*)(p + 63569920);     // 25165824 (Hstart after ph2)
  unsigned short* yg    = (unsigned short*)(p + 88735744);  // 6291456
  unsigned short* x_bf  = (unsigned short*)(p + 95027200);  // 3145728
  unsigned short* WinT  = (unsigned short*)(p + 98172928);  // 4718592
  unsigned short* WoutT = (unsigned short*)(p + 102891520); // 2359296
  unsigned short* WxT   = (unsigned short*)(p + 105250816); // 245760
  float* negA   = (float*)(p + 105496576);    // 98304

  // 1. merged prep
  prep_kernel<<<4416, 256, 0, stream>>>(x, W_in, W_out, W_x, A_log,
                                        x_bf, WinT, WoutT, WxT, negA);
  // 2. x @ W_in -> xi (f32) | res_bf (bf16), 64x128 tile, 768 blocks
  gemm_bf16<2, 4, true><<<dim3(NXR / 128, MROWS / 64), 256, 0, stream>>>(
      x_bf, WinT, xi, res_bf, MROWS, NXR, DM);
  // 3. fused conv+silu+xdbl -> u_bf, xdbl
  mid_kernel<<<MROWS / 16, 256, 0, stream>>>(xi, conv_w, conv_b, WxT, u_bf, xdbl);
  // 4. delta
  delta_kernel<<<dim3(DI / 256, MROWS / DMP), 256, 0, stream>>>(xdbl, W_dt, b_dt, delta);
  // 5. chunked scan (NCHUNK=128, n-major state)
  scan_ph1<<<dim3(DI / SCB, NCHUNK, NBATCH), SCB, 0, stream>>>(
      delta, xdbl, u_bf, negA, Aprod, Hend);
  scan_ph2<<<(NBATCH * DI * NSTATE) / 256, 256, 0, stream>>>(Aprod, Hend);
  scan_ph3<<<dim3(DI / SCB, NCHUNK, NBATCH), SCB, 0, stream>>>(
      delta, xdbl, u_bf, res_bf, negA, Dp, Hend, yg);
  // 6. yg @ W_out -> out
  gemm_bf16<2, 2, false><<<dim3(DM / 64, MROWS / 64), 256, 0, stream>>>(
      yg, WoutT, out, nullptr, MROWS, DM, DI);
}

// Round 14
// 233.780 us; speedup vs baseline: 1.3890x; 1.3890x over previous
//
#include <hip/hip_runtime.h>
#include <math.h>

#define DI 1536
#define DM 768
#define NSTATE 16
#define DTRANK 48
#define LSEQ 1024
#define NBATCH 2
#define MROWS (NBATCH*LSEQ)   // 2048
#define NXR 3072              // 2*DI
#define NCHUNK 128
#define CLEN 8
#define SCB 128               // scan channels per block
#define DMP 16                // delta rows per block
#define ULDS 1544             // padded u-LDS row stride (bf16)

typedef __attribute__((ext_vector_type(4))) float f32x4;
typedef __attribute__((ext_vector_type(8))) short s16x8;
typedef __attribute__((ext_vector_type(4))) unsigned int u32x4;

__device__ __forceinline__ unsigned short f2bf(float f) {
  unsigned int x = __builtin_bit_cast(unsigned int, f);
  return (unsigned short)((x + 0x7fffu + ((x >> 16) & 1u)) >> 16);
}
__device__ __forceinline__ float bf2f(unsigned short b) {
  unsigned int u = ((unsigned int)b) << 16;
  return __builtin_bit_cast(float, u);
}

__device__ __forceinline__ void gload_lds16(const void* g, void* l) {
  __builtin_amdgcn_global_load_lds(
      (const __attribute__((address_space(1))) void*)g,
      (__attribute__((address_space(3))) void*)l, 16, 0, 0);
}

// ---------------- merged prep ----------------
// [0,768) x->bf16 | [768,3072) W_in^T | [3072,4224) W_out^T | [4224,4368) W_x^T
// [4368,4416) negA[n][d] = -exp(A_log[d][n])
__global__ __launch_bounds__(256) void prep_kernel(
    const float* __restrict__ x, const float* __restrict__ W_in,
    const float* __restrict__ W_out, const float* __restrict__ W_x,
    const float* __restrict__ A_log,
    unsigned short* __restrict__ x_bf, unsigned short* __restrict__ WinT,
    unsigned short* __restrict__ WoutT, unsigned short* __restrict__ WxT,
    float* __restrict__ negA)
{
  __shared__ float t[32][33];
  const int bid = blockIdx.x;
  const int tid = threadIdx.x;
  if (bid < 768) {                       // x -> x_bf (8 elems/thread)
    long i = ((long)bid * 256 + tid) * 8;
    f32x4 v0 = *(const f32x4*)&x[i];
    f32x4 v1 = *(const f32x4*)&x[i + 4];
    unsigned short o[8];
    #pragma unroll
    for (int j = 0; j < 4; ++j) { o[j] = f2bf(v0[j]); o[4 + j] = f2bf(v1[j]); }
    *(u32x4*)&x_bf[i] = *(u32x4*)o;
    return;
  }
  int tx = tid & 31, ty = tid >> 5;
  if (bid >= 4368) {                     // A_log [DI][16] -> negA [16][DI]
    int rtile = (bid - 4368) * 32;
    #pragma unroll
    for (int i = 0; i < 4; ++i) {
      int r = ty + i * 8;
      if (tx < 16) t[r][tx] = A_log[(long)(rtile + r) * NSTATE + tx];
    }
    __syncthreads();
    #pragma unroll
    for (int i = 0; i < 2; ++i) {
      int cc = ty + i * 8;               // 0..15
      negA[(long)cc * DI + rtile + tx] = -__expf(t[tx][cc]);
    }
    return;
  }
  const float* in; unsigned short* out; int R, C, bx, by; bool guard = false;
  if (bid < 3072)      { int q = bid - 768;  in = W_in;  out = WinT;  R = DM; C = NXR; bx = q % 96; by = q / 96; }
  else if (bid < 4224) { int q = bid - 3072; in = W_out; out = WoutT; R = DI; C = DM;  bx = q % 24; by = q / 24; }
  else                 { int q = bid - 4224; in = W_x;   out = WxT;   R = DI; C = 80;  bx = q % 3;  by = q / 3; guard = true; }
  int ctile = bx * 32, rtile = by * 32;
  #pragma unroll
  for (int i = 0; i < 4; ++i) {
    int r = ty + i * 8;
    if (!guard || (rtile + r < R && ctile + tx < C))
      t[r][tx] = in[(long)(rtile + r) * C + ctile + tx];
  }
  __syncthreads();
  #pragma unroll
  for (int i = 0; i < 4; ++i) {
    int cc = ty + i * 8;
    if (!guard || (ctile + cc < C && rtile + tx < R))
      out[(long)(ctile + cc) * R + rtile + tx] = f2bf(t[tx][cc]);
  }
}

// ---------------- bf16 MFMA GEMM: C = A @ BT^T ----------------
// SPLIT=true (gemm1): cols < DI -> f32 xi[m][DI]; cols >= DI -> bf16 res_bf[m][DI]
template<int FM, int FN, bool SPLIT>
__global__ __launch_bounds__(256) void gemm_bf16(
    const unsigned short* __restrict__ A,
    const unsigned short* __restrict__ BT,
    float* __restrict__ C,               // SPLIT: xi buffer
    unsigned short* __restrict__ res_bf, // SPLIT only
    int M, int N, int K)
{
  constexpr int BM = 32 * FM, BN = 32 * FN;
  constexpr int TM = BM / 16, TN = BN / 16;
  __shared__ unsigned short Ap[BM * 32];
  __shared__ unsigned short Bp[BN * 32];
  const int tid = threadIdx.x;
  const int lane = tid & 63, wave = tid >> 6;
  const int wr = wave >> 1, wc = wave & 1;
  const int lg = lane >> 4, lr = lane & 15;
  const int m0 = blockIdx.y * BM, n0 = blockIdx.x * BN;
  f32x4 acc[FM][FN] = {};
  for (int k0 = 0; k0 < K; k0 += 32) {
    #pragma unroll
    for (int p = 0; p < TM / 4; ++p) {
      int tile = wave + p * 4;
      gload_lds16(&A[(long)(m0 + tile * 16 + lr) * K + k0 + lg * 8], &Ap[tile * 512]);
    }
    #pragma unroll
    for (int p = 0; p < TN / 4; ++p) {
      int tile = wave + p * 4;
      gload_lds16(&BT[(long)(n0 + tile * 16 + lr) * K + k0 + lg * 8], &Bp[tile * 512]);
    }
    __syncthreads();
    s16x8 af[FM], bfr[FN];
    #pragma unroll
    for (int m = 0; m < FM; ++m)
      af[m] = *(s16x8*)&Ap[(((wr * FM + m) * 4 + lg) * 16 + lr) * 8];
    #pragma unroll
    for (int n = 0; n < FN; ++n)
      bfr[n] = *(s16x8*)&Bp[(((wc * FN + n) * 4 + lg) * 16 + lr) * 8];
    #pragma unroll
    for (int m = 0; m < FM; ++m)
      #pragma unroll
      for (int n = 0; n < FN; ++n)
        acc[m][n] = __builtin_amdgcn_mfma_f32_16x16x32_bf16(af[m], bfr[n], acc[m][n], 0, 0, 0);
    __syncthreads();
  }
  #pragma unroll
  for (int m = 0; m < FM; ++m)
    #pragma unroll
    for (int n = 0; n < FN; ++n)
      #pragma unroll
      for (int r = 0; r < 4; ++r) {
        int row = m0 + wr * 16 * FM + m * 16 + lg * 4 + r;
        int col = n0 + wc * 16 * FN + n * 16 + lr;
        if (SPLIT) {
          if (n0 < DI) C[(long)row * DI + col] = acc[m][n][r];
          else res_bf[(long)row * DI + col - DI] = f2bf(acc[m][n][r]);
        } else {
          C[(long)row * N + col] = acc[m][n][r];
        }
      }
}

// ---------------- fused conv+silu + xdbl MFMA ----------------
// grid MROWS/16 = 128 blocks, 256 thr. Block owns rows m0..m0+15.
__global__ __launch_bounds__(256) void mid_kernel(
    const float* __restrict__ xi,
    const float* __restrict__ conv_w,
    const float* __restrict__ conv_b,
    const unsigned short* __restrict__ WxT,
    unsigned short* __restrict__ u_bf,
    float* __restrict__ xdbl)
{
  __shared__ __align__(16) char smem[16 * ULDS * 2];   // 49408 B
  unsigned short* uL = (unsigned short*)smem;           // [16][ULDS] bf16
  float* red = (float*)smem;                            // [4][16][80] f32 (aliases uL after B reads)
  const int tid = threadIdx.x;
  const int m0 = blockIdx.x * 16;
  // ---- phase A: conv + bias + silu ----
  for (int i = tid; i < 16 * DI; i += 256) {
    int row = i / DI, col = i - row * DI;
    int m = m0 + row;
    int t = m % LSEQ;
    float w0 = conv_w[col * 4 + 0], w1 = conv_w[col * 4 + 1];
    float w2 = conv_w[col * 4 + 2], w3 = conv_w[col * 4 + 3];
    float acc = conv_b[col];
    if (t >= 3) acc = fmaf(xi[(long)(m - 3) * DI + col], w0, acc);
    if (t >= 2) acc = fmaf(xi[(long)(m - 2) * DI + col], w1, acc);
    if (t >= 1) acc = fmaf(xi[(long)(m - 1) * DI + col], w2, acc);
    acc = fmaf(xi[(long)m * DI + col], w3, acc);
    float s = acc / (1.f + __expf(-acc));
    unsigned short bv = f2bf(s);
    uL[row * ULDS + col] = bv;
    u_bf[(long)m * DI + col] = bv;
  }
  __syncthreads();
  // ---- phase B: MFMA, 4 waves split K ----
  const int lane = tid & 63, wave = tid >> 6;
  const int lg = lane >> 4, lr = lane & 15;
  f32x4 acc[5] = {};
  const int kbase = wave * (DI / 4);
  #pragma unroll
  for (int kk = 0; kk < DI / 4; kk += 32) {
    int k0 = kbase + kk;
    s16x8 af = *(const s16x8*)&uL[lr * ULDS + k0 + lg * 8];
    #pragma unroll
    for (int n = 0; n < 5; ++n) {
      s16x8 bfr = *(const s16x8*)&WxT[(long)(n * 16 + lr) * DI + k0 + lg * 8];
      acc[n] = __builtin_amdgcn_mfma_f32_16x16x32_bf16(af, bfr, acc[n], 0, 0, 0);
    }
  }
  __syncthreads();   // all uL reads done -> safe to overwrite with red
  #pragma unroll
  for (int n = 0; n < 5; ++n)
    #pragma unroll
    for (int r = 0; r < 4; ++r)
      red[(wave * 16 + lg * 4 + r) * 80 + n * 16 + lr] = acc[n][r];
  __syncthreads();
  for (int i = tid; i < 16 * 80; i += 256) {
    int row = i / 80, col = i - row * 80;
    float s = red[(0 * 16 + row) * 80 + col] + red[(1 * 16 + row) * 80 + col]
            + red[(2 * 16 + row) * 80 + col] + red[(3 * 16 + row) * 80 + col];
    xdbl[(long)(m0 + row) * 80 + col] = s;
  }
}

// ---------------- delta = softplus(xdbl[:, :48] @ W_dt + b_dt) ----------------
// round-11 proven form: scalar LDS broadcast reads, VGPR ~32.
__global__ __launch_bounds__(256) void delta_kernel(
    const float* __restrict__ xdbl,
    const float* __restrict__ W_dt,
    const float* __restrict__ b_dt,
    float* __restrict__ delta)
{
  __shared__ float sx[DMP][DTRANK];
  const int tid = threadIdx.x;
  const int c = blockIdx.x * 256 + tid;
  const int m0 = blockIdx.y * DMP;
  for (int i = tid; i < DMP * DTRANK; i += 256) {
    int mm = i / DTRANK, r = i % DTRANK;
    sx[mm][r] = xdbl[(long)(m0 + mm) * 80 + r];
  }
  __syncthreads();
  float bias = b_dt[c];
  float acc[DMP];
  #pragma unroll
  for (int mm = 0; mm < DMP; ++mm) acc[mm] = bias;
  for (int r = 0; r < DTRANK; ++r) {
    float wv = W_dt[(long)r * DI + c];
    #pragma unroll
    for (int mm = 0; mm < DMP; ++mm)
      acc[mm] = fmaf(sx[mm][r], wv, acc[mm]);
  }
  #pragma unroll
  for (int mm = 0; mm < DMP; ++mm) {
    float v = acc[mm];
    float sp = (v > 20.f) ? v : log1pf(__expf(v));
    delta[(long)(m0 + mm) * DI + c] = sp;
  }
}

// ---------------- scan phase 1: n-major state, coalesced stores ----------------
// grid (DI/SCB=12, NCHUNK=128, NBATCH), block SCB=128. round-11 body.
__global__ __launch_bounds__(SCB) void scan_ph1(
    const float* __restrict__ delta,
    const float* __restrict__ xdbl,
    const unsigned short* __restrict__ u_bf,
    const float* __restrict__ negA,
    float* __restrict__ Aprod,
    float* __restrict__ Hend)
{
  const int b = blockIdx.z, chunk = blockIdx.y;
  const int tid = threadIdx.x;
  const int d = blockIdx.x * SCB + tid;
  const long mbase = (long)b * LSEQ + chunk * CLEN;
  __shared__ float sB[CLEN][NSTATE];
  for (int i = tid; i < CLEN * NSTATE; i += SCB) {
    int t = i >> 4, j = i & 15;
    sB[t][j] = xdbl[(mbase + t) * 80 + DTRANK + j];
  }
  __syncthreads();
  float a[NSTATE];
  #pragma unroll
  for (int n = 0; n < NSTATE; ++n)
    a[n] = negA[(long)n * DI + d];
  float h[NSTATE] = {};
  float Ap[NSTATE];
  #pragma unroll
  for (int n = 0; n < NSTATE; ++n) Ap[n] = 1.f;
  #pragma unroll
  for (int t = 0; t < CLEN; ++t) {
    long m = mbase + t;
    float dt = delta[m * DI + d];
    float uu = bf2f(u_bf[m * DI + d]);
    float dtu = dt * uu;
    #pragma unroll
    for (int n = 0; n < NSTATE; ++n) {
      float dA = __expf(dt * a[n]);
      Ap[n] *= dA;
      h[n] = fmaf(dA, h[n], dtu * sB[t][n]);
    }
  }
  const long o = ((long)(b * NCHUNK + chunk) * NSTATE) * DI + d;
  #pragma unroll
  for (int n = 0; n < NSTATE; ++n) {
    Aprod[o + (long)n * DI] = Ap[n];
    Hend[o + (long)n * DI] = h[n];
  }
}

// ---------------- scan phase 2: prefix across chunks; Hend -> Hstart in place ----------------
__global__ __launch_bounds__(256) void scan_ph2(
    const float* __restrict__ Aprod,
    float* __restrict__ Hend)
{
  int idx = blockIdx.x * 256 + threadIdx.x;   // [0, 2*1536*16)
  int b = idx / (DI * NSTATE);
  int r = idx % (DI * NSTATE);
  long o = (long)b * NCHUNK * DI * NSTATE + r;
  const long stride = (long)DI * NSTATE;
  float h = 0.f;
  for (int c = 0; c < NCHUNK; ++c) {
    float Ap = Aprod[o + c * stride];
    float He = Hend[o + c * stride];
    Hend[o + c * stride] = h;
    h = fmaf(Ap, h, He);
  }
}

// ---------------- scan phase 3: replay + y + gate -> yg (bf16). round-11 body ----------------
__global__ __launch_bounds__(SCB) void scan_ph3(
    const float* __restrict__ delta,
    const float* __restrict__ xdbl,
    const unsigned short* __restrict__ u_bf,
    const unsigned short* __restrict__ res_bf,
    const float* __restrict__ negA,
    const float* __restrict__ Dp,
    const float* __restrict__ Hstart,  // = Hend buffer after ph2
    unsigned short* __restrict__ yg)
{
  const int b = blockIdx.z, chunk = blockIdx.y;
  const int tid = threadIdx.x;
  const int d = blockIdx.x * SCB + tid;
  const long mbase = (long)b * LSEQ + chunk * CLEN;
  __shared__ float sB[CLEN][NSTATE], sC[CLEN][NSTATE];
  for (int i = tid; i < CLEN * NSTATE; i += SCB) {
    int t = i >> 4, j = i & 15;
    long mo = (mbase + t) * 80 + DTRANK + j;
    sB[t][j] = xdbl[mo];
    sC[t][j] = xdbl[mo + NSTATE];
  }
  __syncthreads();
  float a[NSTATE];
  #pragma unroll
  for (int n = 0; n < NSTATE; ++n)
    a[n] = negA[(long)n * DI + d];
  const float Dv = Dp[d];
  const long o = ((long)(b * NCHUNK + chunk) * NSTATE) * DI + d;
  float h[NSTATE];
  #pragma unroll
  for (int n = 0; n < NSTATE; ++n)
    h[n] = Hstart[o + (long)n * DI];
  #pragma unroll
  for (int t = 0; t < CLEN; ++t) {
    long m = mbase + t;
    float dt = delta[m * DI + d];
    float uu = bf2f(u_bf[m * DI + d]);
    float rr = bf2f(res_bf[m * DI + d]);
    float dtu = dt * uu;
    float p0 = 0.f, p1 = 0.f, p2 = 0.f, p3 = 0.f;
    #pragma unroll
    for (int q = 0; q < 4; ++q) {
      float dA0 = __expf(dt * a[q*4+0]);
      float dA1 = __expf(dt * a[q*4+1]);
      float dA2 = __expf(dt * a[q*4+2]);
      float dA3 = __expf(dt * a[q*4+3]);
      h[q*4+0] = fmaf(dA0, h[q*4+0], dtu * sB[t][q*4+0]);
      h[q*4+1] = fmaf(dA1, h[q*4+1], dtu * sB[t][q*4+1]);
      h[q*4+2] = fmaf(dA2, h[q*4+2], dtu * sB[t][q*4+2]);
      h[q*4+3] = fmaf(dA3, h[q*4+3], dtu * sB[t][q*4+3]);
    }
    #pragma unroll
    for (int n = 0; n < NSTATE; n += 4) {
      p0 = fmaf(h[n+0], sC[t][n+0], p0);
      p1 = fmaf(h[n+1], sC[t][n+1], p1);
      p2 = fmaf(h[n+2], sC[t][n+2], p2);
      p3 = fmaf(h[n+3], sC[t][n+3], p3);
    }
    float yv = (p0 + p1) + (p2 + p3) + uu * Dv;
    float gate = rr / (1.f + __expf(-rr));
    yg[m * DI + d] = f2bf(yv * gate);
  }
}

// ---------------- launch ----------------
extern "C" void kernel_launch(void* const* d_in, const int* in_sizes, int n_in,
                              void* d_out, int out_size, void* d_ws, size_t ws_size,
                              hipStream_t stream)
{
  const float* x      = (const float*)d_in[0];
  const float* W_in   = (const float*)d_in[1];
  const float* conv_w = (const float*)d_in[2];
  const float* conv_b = (const float*)d_in[3];
  const float* W_x    = (const float*)d_in[4];
  const float* W_dt   = (const float*)d_in[5];
  const float* b_dt   = (const float*)d_in[6];
  const float* A_log  = (const float*)d_in[7];
  const float* Dp     = (const float*)d_in[8];
  const float* W_out  = (const float*)d_in[9];
  float* out = (float*)d_out;

  char* p = (char*)d_ws;   // ws = 256 MiB
  float* xi     = (float*)(p + 0);            // 12582912
  unsigned short* res_bf = (unsigned short*)(p + 12582912);  // 6291456
  unsigned short* u_bf   = (unsigned short*)(p + 18874368);  // 6291456
  float* xdbl   = (float*)(p + 25165824);     // 655360
  float* delta  = (float*)(p + 25821184);     // 12582912
  float* Aprod  = (float*)(p + 38404096);     // 25165824 (NCHUNK=128)
  float* Hend   = (float*)(p + 63569920);     // 25165824 (Hstart after ph2)
  unsigned short* yg    = (unsigned short*)(p + 88735744);  // 6291456
  unsigned short* x_bf  = (unsigned short*)(p + 95027200);  // 3145728
  unsigned short* WinT  = (unsigned short*)(p + 98172928);  // 4718592
  unsigned short* WoutT = (unsigned short*)(p + 102891520); // 2359296
  unsigned short* WxT   = (unsigned short*)(p + 105250816); // 245760
  float* negA   = (float*)(p + 105496576);    // 98304

  // 1. merged prep
  prep_kernel<<<4416, 256, 0, stream>>>(x, W_in, W_out, W_x, A_log,
                                        x_bf, WinT, WoutT, WxT, negA);
  // 2. x @ W_in -> xi (f32) | res_bf (bf16), 64x128 tile, 768 blocks
  gemm_bf16<2, 4, true><<<dim3(NXR / 128, MROWS / 64), 256, 0, stream>>>(
      x_bf, WinT, xi, res_bf, MROWS, NXR, DM);
  // 3. fused conv+silu+xdbl -> u_bf, xdbl
  mid_kernel<<<MROWS / 16, 256, 0, stream>>>(xi, conv_w, conv_b, WxT, u_bf, xdbl);
  // 4. delta
  delta_kernel<<<dim3(DI / 256, MROWS / DMP), 256, 0, stream>>>(xdbl, W_dt, b_dt, delta);
  // 5. chunked scan (NCHUNK=128, n-major state)
  scan_ph1<<<dim3(DI / SCB, NCHUNK, NBATCH), SCB, 0, stream>>>(
      delta, xdbl, u_bf, negA, Aprod, Hend);
  scan_ph2<<<(NBATCH * DI * NSTATE) / 256, 256, 0, stream>>>(Aprod, Hend);
  scan_ph3<<<dim3(DI / SCB, NCHUNK, NBATCH), SCB, 0, stream>>>(
      delta, xdbl, u_bf, res_bf, negA, Dp, Hend, yg);
  // 6. yg @ W_out -> out
  gemm_bf16<2, 2, false><<<dim3(DM / 64, MROWS / 64), 256, 0, stream>>>(
      yg, WoutT, out, nullptr, MROWS, DM, DI);
}

// Round 15
// 160.552 us; speedup vs baseline: 2.0225x; 1.4561x over previous
//
#include <hip/hip_runtime.h>
#include <math.h>

#define DI 1536
#define DM 768
#define NSTATE 16
#define DTRANK 48
#define LSEQ 1024
#define NBATCH 2
#define MROWS (NBATCH*LSEQ)   // 2048
#define NXR 3072              // 2*DI
#define NCHUNK 128
#define CLEN 8
#define SCB 128               // scan channels per block
#define DMP 16                // delta rows per block

typedef __attribute__((ext_vector_type(4))) float f32x4;
typedef __attribute__((ext_vector_type(8))) short s16x8;
typedef __attribute__((ext_vector_type(4))) unsigned int u32x4;

__device__ __forceinline__ unsigned short f2bf(float f) {
  unsigned int x = __builtin_bit_cast(unsigned int, f);
  return (unsigned short)((x + 0x7fffu + ((x >> 16) & 1u)) >> 16);
}
__device__ __forceinline__ float bf2f(unsigned short b) {
  unsigned int u = ((unsigned int)b) << 16;
  return __builtin_bit_cast(float, u);
}

__device__ __forceinline__ void gload_lds16(const void* g, void* l) {
  __builtin_amdgcn_global_load_lds(
      (const __attribute__((address_space(1))) void*)g,
      (__attribute__((address_space(3))) void*)l, 16, 0, 0);
}

// ---------------- merged prep ----------------
// [0,768) x->bf16 | [768,3072) W_in^T | [3072,4224) W_out^T | [4224,4368) W_x^T
// [4368,4416) negA[n][d] = -exp(A_log[d][n])
__global__ __launch_bounds__(256) void prep_kernel(
    const float* __restrict__ x, const float* __restrict__ W_in,
    const float* __restrict__ W_out, const float* __restrict__ W_x,
    const float* __restrict__ A_log,
    unsigned short* __restrict__ x_bf, unsigned short* __restrict__ WinT,
    unsigned short* __restrict__ WoutT, unsigned short* __restrict__ WxT,
    float* __restrict__ negA)
{
  __shared__ float t[32][33];
  const int bid = blockIdx.x;
  const int tid = threadIdx.x;
  if (bid < 768) {                       // x -> x_bf (8 elems/thread)
    long i = ((long)bid * 256 + tid) * 8;
    f32x4 v0 = *(const f32x4*)&x[i];
    f32x4 v1 = *(const f32x4*)&x[i + 4];
    unsigned short o[8];
    #pragma unroll
    for (int j = 0; j < 4; ++j) { o[j] = f2bf(v0[j]); o[4 + j] = f2bf(v1[j]); }
    *(u32x4*)&x_bf[i] = *(u32x4*)o;
    return;
  }
  int tx = tid & 31, ty = tid >> 5;
  if (bid >= 4368) {                     // A_log [DI][16] -> negA [16][DI]
    int rtile = (bid - 4368) * 32;
    #pragma unroll
    for (int i = 0; i < 4; ++i) {
      int r = ty + i * 8;
      if (tx < 16) t[r][tx] = A_log[(long)(rtile + r) * NSTATE + tx];
    }
    __syncthreads();
    #pragma unroll
    for (int i = 0; i < 2; ++i) {
      int cc = ty + i * 8;               // 0..15
      negA[(long)cc * DI + rtile + tx] = -__expf(t[tx][cc]);
    }
    return;
  }
  const float* in; unsigned short* out; int R, C, bx, by; bool guard = false;
  if (bid < 3072)      { int q = bid - 768;  in = W_in;  out = WinT;  R = DM; C = NXR; bx = q % 96; by = q / 96; }
  else if (bid < 4224) { int q = bid - 3072; in = W_out; out = WoutT; R = DI; C = DM;  bx = q % 24; by = q / 24; }
  else                 { int q = bid - 4224; in = W_x;   out = WxT;   R = DI; C = 80;  bx = q % 3;  by = q / 3; guard = true; }
  int ctile = bx * 32, rtile = by * 32;
  #pragma unroll
  for (int i = 0; i < 4; ++i) {
    int r = ty + i * 8;
    if (!guard || (rtile + r < R && ctile + tx < C))
      t[r][tx] = in[(long)(rtile + r) * C + ctile + tx];
  }
  __syncthreads();
  #pragma unroll
  for (int i = 0; i < 4; ++i) {
    int cc = ty + i * 8;
    if (!guard || (ctile + cc < C && rtile + tx < R))
      out[(long)(ctile + cc) * R + rtile + tx] = f2bf(t[tx][cc]);
  }
}

// ---------------- bf16 MFMA GEMM: C = A @ BT^T ----------------
// SPLIT=true (gemm1): cols < DI -> f32 xi[m][DI]; cols >= DI -> bf16 res_bf[m][DI]
template<int FM, int FN, bool SPLIT>
__global__ __launch_bounds__(256) void gemm_bf16(
    const unsigned short* __restrict__ A,
    const unsigned short* __restrict__ BT,
    float* __restrict__ C,               // SPLIT: xi buffer
    unsigned short* __restrict__ res_bf, // SPLIT only
    int M, int N, int K)
{
  constexpr int BM = 32 * FM, BN = 32 * FN;
  constexpr int TM = BM / 16, TN = BN / 16;
  __shared__ unsigned short Ap[BM * 32];
  __shared__ unsigned short Bp[BN * 32];
  const int tid = threadIdx.x;
  const int lane = tid & 63, wave = tid >> 6;
  const int wr = wave >> 1, wc = wave & 1;
  const int lg = lane >> 4, lr = lane & 15;
  const int m0 = blockIdx.y * BM, n0 = blockIdx.x * BN;
  f32x4 acc[FM][FN] = {};
  for (int k0 = 0; k0 < K; k0 += 32) {
    #pragma unroll
    for (int p = 0; p < TM / 4; ++p) {
      int tile = wave + p * 4;
      gload_lds16(&A[(long)(m0 + tile * 16 + lr) * K + k0 + lg * 8], &Ap[tile * 512]);
    }
    #pragma unroll
    for (int p = 0; p < TN / 4; ++p) {
      int tile = wave + p * 4;
      gload_lds16(&BT[(long)(n0 + tile * 16 + lr) * K + k0 + lg * 8], &Bp[tile * 512]);
    }
    __syncthreads();
    s16x8 af[FM], bfr[FN];
    #pragma unroll
    for (int m = 0; m < FM; ++m)
      af[m] = *(s16x8*)&Ap[(((wr * FM + m) * 4 + lg) * 16 + lr) * 8];
    #pragma unroll
    for (int n = 0; n < FN; ++n)
      bfr[n] = *(s16x8*)&Bp[(((wc * FN + n) * 4 + lg) * 16 + lr) * 8];
    #pragma unroll
    for (int m = 0; m < FM; ++m)
      #pragma unroll
      for (int n = 0; n < FN; ++n)
        acc[m][n] = __builtin_amdgcn_mfma_f32_16x16x32_bf16(af[m], bfr[n], acc[m][n], 0, 0, 0);
    __syncthreads();
  }
  #pragma unroll
  for (int m = 0; m < FM; ++m)
    #pragma unroll
    for (int n = 0; n < FN; ++n)
      #pragma unroll
      for (int r = 0; r < 4; ++r) {
        int row = m0 + wr * 16 * FM + m * 16 + lg * 4 + r;
        int col = n0 + wc * 16 * FN + n * 16 + lr;
        if (SPLIT) {
          if (n0 < DI) C[(long)row * DI + col] = acc[m][n][r];
          else res_bf[(long)row * DI + col - DI] = f2bf(acc[m][n][r]);
        } else {
          C[(long)row * N + col] = acc[m][n][r];
        }
      }
}

// ---------------- depthwise causal conv(4) + bias + SiLU -> u_bf ----------------
__global__ __launch_bounds__(256) void conv_silu_kernel(
    const float* __restrict__ xi,
    const float* __restrict__ conv_w,
    const float* __restrict__ conv_b,
    unsigned short* __restrict__ u_bf)
{
  int idx = blockIdx.x * 256 + threadIdx.x;
  if (idx >= MROWS * DI) return;
  int c = idx % DI;
  int m = idx / DI;
  int t = m % LSEQ;
  float w0 = conv_w[c * 4 + 0], w1 = conv_w[c * 4 + 1];
  float w2 = conv_w[c * 4 + 2], w3 = conv_w[c * 4 + 3];
  float acc = conv_b[c];
  if (t >= 3) acc = fmaf(xi[(long)(m - 3) * DI + c], w0, acc);
  if (t >= 2) acc = fmaf(xi[(long)(m - 2) * DI + c], w1, acc);
  if (t >= 1) acc = fmaf(xi[(long)(m - 1) * DI + c], w2, acc);
  acc = fmaf(xi[(long)m * DI + c], w3, acc);
  float s = acc / (1.f + __expf(-acc));
  u_bf[idx] = f2bf(s);
}

// ---------------- x_dbl = u @ W_x via MFMA; BM=16, 4 waves split K ----------------
__global__ __launch_bounds__(256) void xdbl_mfma(
    const unsigned short* __restrict__ u_bf,
    const unsigned short* __restrict__ WxT,
    float* __restrict__ xdbl)
{
  const int tid = threadIdx.x;
  const int lane = tid & 63, wave = tid >> 6;
  const int lg = lane >> 4, lr = lane & 15;
  const int m0 = blockIdx.x * 16;
  f32x4 acc[5] = {};
  const int kbase = wave * (DI / 4);
  #pragma unroll
  for (int kk = 0; kk < DI / 4; kk += 32) {
    int k0 = kbase + kk;
    s16x8 af = *(const s16x8*)&u_bf[(long)(m0 + lr) * DI + k0 + lg * 8];
    #pragma unroll
    for (int n = 0; n < 5; ++n) {
      s16x8 bfr = *(const s16x8*)&WxT[(long)(n * 16 + lr) * DI + k0 + lg * 8];
      acc[n] = __builtin_amdgcn_mfma_f32_16x16x32_bf16(af, bfr, acc[n], 0, 0, 0);
    }
  }
  __shared__ float red[4][16][80];
  #pragma unroll
  for (int n = 0; n < 5; ++n)
    #pragma unroll
    for (int r = 0; r < 4; ++r)
      red[wave][lg * 4 + r][n * 16 + lr] = acc[n][r];
  __syncthreads();
  for (int i = tid; i < 16 * 80; i += 256) {
    int row = i / 80, col = i % 80;
    float s = red[0][row][col] + red[1][row][col] + red[2][row][col] + red[3][row][col];
    xdbl[(long)(m0 + row) * 80 + col] = s;
  }
}

// ---------------- delta = softplus(xdbl[:, :48] @ W_dt + b_dt) ----------------
// 16 m-rows per block; W_dt element read once per 16 rows. VGPR ~32.
__global__ __launch_bounds__(256) void delta_kernel(
    const float* __restrict__ xdbl,
    const float* __restrict__ W_dt,
    const float* __restrict__ b_dt,
    float* __restrict__ delta)
{
  __shared__ float sx[DMP][DTRANK];
  const int tid = threadIdx.x;
  const int c = blockIdx.x * 256 + tid;
  const int m0 = blockIdx.y * DMP;
  for (int i = tid; i < DMP * DTRANK; i += 256) {
    int mm = i / DTRANK, r = i % DTRANK;
    sx[mm][r] = xdbl[(long)(m0 + mm) * 80 + r];
  }
  __syncthreads();
  float bias = b_dt[c];
  float acc[DMP];
  #pragma unroll
  for (int mm = 0; mm < DMP; ++mm) acc[mm] = bias;
  for (int r = 0; r < DTRANK; ++r) {
    float wv = W_dt[(long)r * DI + c];
    #pragma unroll
    for (int mm = 0; mm < DMP; ++mm)
      acc[mm] = fmaf(sx[mm][r], wv, acc[mm]);
  }
  #pragma unroll
  for (int mm = 0; mm < DMP; ++mm) {
    float v = acc[mm];
    float sp = (v > 20.f) ? v : log1pf(__expf(v));
    delta[(long)(m0 + mm) * DI + c] = sp;
  }
}

// ---------------- scan phase 1: n-major state, coalesced stores ----------------
// grid (DI/SCB=12, NCHUNK=128, NBATCH), block SCB=128
__global__ __launch_bounds__(SCB) void scan_ph1(
    const float* __restrict__ delta,
    const float* __restrict__ xdbl,
    const unsigned short* __restrict__ u_bf,
    const float* __restrict__ negA,
    float* __restrict__ Aprod,
    float* __restrict__ Hend)
{
  const int b = blockIdx.z, chunk = blockIdx.y;
  const int tid = threadIdx.x;
  const int d = blockIdx.x * SCB + tid;
  const long mbase = (long)b * LSEQ + chunk * CLEN;
  __shared__ float sB[CLEN][NSTATE];
  for (int i = tid; i < CLEN * NSTATE; i += SCB) {
    int t = i >> 4, j = i & 15;
    sB[t][j] = xdbl[(mbase + t) * 80 + DTRANK + j];
  }
  __syncthreads();
  float a[NSTATE];
  #pragma unroll
  for (int n = 0; n < NSTATE; ++n)
    a[n] = negA[(long)n * DI + d];
  float h[NSTATE] = {};
  float Ap[NSTATE];
  #pragma unroll
  for (int n = 0; n < NSTATE; ++n) Ap[n] = 1.f;
  #pragma unroll
  for (int t = 0; t < CLEN; ++t) {
    long m = mbase + t;
    float dt = delta[m * DI + d];
    float uu = bf2f(u_bf[m * DI + d]);
    float dtu = dt * uu;
    #pragma unroll
    for (int n = 0; n < NSTATE; ++n) {
      float dA = __expf(dt * a[n]);
      Ap[n] *= dA;
      h[n] = fmaf(dA, h[n], dtu * sB[t][n]);
    }
  }
  const long o = ((long)(b * NCHUNK + chunk) * NSTATE) * DI + d;
  #pragma unroll
  for (int n = 0; n < NSTATE; ++n) {
    Aprod[o + (long)n * DI] = Ap[n];
    Hend[o + (long)n * DI] = h[n];
  }
}

// ---------------- scan phase 2: prefix across chunks; Hend -> Hstart in place ----------------
__global__ __launch_bounds__(256) void scan_ph2(
    const float* __restrict__ Aprod,
    float* __restrict__ Hend)
{
  int idx = blockIdx.x * 256 + threadIdx.x;   // [0, 2*1536*16)
  int b = idx / (DI * NSTATE);
  int r = idx % (DI * NSTATE);
  long o = (long)b * NCHUNK * DI * NSTATE + r;
  const long stride = (long)DI * NSTATE;
  float h = 0.f;
  for (int c = 0; c < NCHUNK; ++c) {
    float Ap = Aprod[o + c * stride];
    float He = Hend[o + c * stride];
    Hend[o + c * stride] = h;
    h = fmaf(Ap, h, He);
  }
}

// ---------------- scan phase 3: replay + y + gate -> yg (bf16) ----------------
__global__ __launch_bounds__(SCB) void scan_ph3(
    const float* __restrict__ delta,
    const float* __restrict__ xdbl,
    const unsigned short* __restrict__ u_bf,
    const unsigned short* __restrict__ res_bf,
    const float* __restrict__ negA,
    const float* __restrict__ Dp,
    const float* __restrict__ Hstart,  // = Hend buffer after ph2
    unsigned short* __restrict__ yg)
{
  const int b = blockIdx.z, chunk = blockIdx.y;
  const int tid = threadIdx.x;
  const int d = blockIdx.x * SCB + tid;
  const long mbase = (long)b * LSEQ + chunk * CLEN;
  __shared__ float sB[CLEN][NSTATE], sC[CLEN][NSTATE];
  for (int i = tid; i < CLEN * NSTATE; i += SCB) {
    int t = i >> 4, j = i & 15;
    long mo = (mbase + t) * 80 + DTRANK + j;
    sB[t][j] = xdbl[mo];
    sC[t][j] = xdbl[mo + NSTATE];
  }
  __syncthreads();
  float a[NSTATE];
  #pragma unroll
  for (int n = 0; n < NSTATE; ++n)
    a[n] = negA[(long)n * DI + d];
  const float Dv = Dp[d];
  const long o = ((long)(b * NCHUNK + chunk) * NSTATE) * DI + d;
  float h[NSTATE];
  #pragma unroll
  for (int n = 0; n < NSTATE; ++n)
    h[n] = Hstart[o + (long)n * DI];
  #pragma unroll
  for (int t = 0; t < CLEN; ++t) {
    long m = mbase + t;
    float dt = delta[m * DI + d];
    float uu = bf2f(u_bf[m * DI + d]);
    float rr = bf2f(res_bf[m * DI + d]);
    float dtu = dt * uu;
    float p0 = 0.f, p1 = 0.f, p2 = 0.f, p3 = 0.f;
    #pragma unroll
    for (int q = 0; q < 4; ++q) {
      float dA0 = __expf(dt * a[q*4+0]);
      float dA1 = __expf(dt * a[q*4+1]);
      float dA2 = __expf(dt * a[q*4+2]);
      float dA3 = __expf(dt * a[q*4+3]);
      h[q*4+0] = fmaf(dA0, h[q*4+0], dtu * sB[t][q*4+0]);
      h[q*4+1] = fmaf(dA1, h[q*4+1], dtu * sB[t][q*4+1]);
      h[q*4+2] = fmaf(dA2, h[q*4+2], dtu * sB[t][q*4+2]);
      h[q*4+3] = fmaf(dA3, h[q*4+3], dtu * sB[t][q*4+3]);
    }
    #pragma unroll
    for (int n = 0; n < NSTATE; n += 4) {
      p0 = fmaf(h[n+0], sC[t][n+0], p0);
      p1 = fmaf(h[n+1], sC[t][n+1], p1);
      p2 = fmaf(h[n+2], sC[t][n+2], p2);
      p3 = fmaf(h[n+3], sC[t][n+3], p3);
    }
    float yv = (p0 + p1) + (p2 + p3) + uu * Dv;
    float gate = rr / (1.f + __expf(-rr));
    yg[m * DI + d] = f2bf(yv * gate);
  }
}

// ---------------- launch ----------------
extern "C" void kernel_launch(void* const* d_in, const int* in_sizes, int n_in,
                              void* d_out, int out_size, void* d_ws, size_t ws_size,
                              hipStream_t stream)
{
  const float* x      = (const float*)d_in[0];
  const float* W_in   = (const float*)d_in[1];
  const float* conv_w = (const float*)d_in[2];
  const float* conv_b = (const float*)d_in[3];
  const float* W_x    = (const float*)d_in[4];
  const float* W_dt   = (const float*)d_in[5];
  const float* b_dt   = (const float*)d_in[6];
  const float* A_log  = (const float*)d_in[7];
  const float* Dp     = (const float*)d_in[8];
  const float* W_out  = (const float*)d_in[9];
  float* out = (float*)d_out;

  char* p = (char*)d_ws;   // ws = 256 MiB
  float* xi     = (float*)(p + 0);            // 12582912
  unsigned short* res_bf = (unsigned short*)(p + 12582912);  // 6291456
  unsigned short* u_bf   = (unsigned short*)(p + 18874368);  // 6291456
  float* xdbl   = (float*)(p + 25165824);     // 655360
  float* delta  = (float*)(p + 25821184);     // 12582912
  float* Aprod  = (float*)(p + 38404096);     // 25165824 (NCHUNK=128)
  float* Hend   = (float*)(p + 63569920);     // 25165824 (Hstart after ph2)
  unsigned short* yg    = (unsigned short*)(p + 88735744);  // 6291456
  unsigned short* x_bf  = (unsigned short*)(p + 95027200);  // 3145728
  unsigned short* WinT  = (unsigned short*)(p + 98172928);  // 4718592
  unsigned short* WoutT = (unsigned short*)(p + 102891520); // 2359296
  unsigned short* WxT   = (unsigned short*)(p + 105250816); // 245760
  float* negA   = (float*)(p + 105496576);    // 98304

  // 1. merged prep
  prep_kernel<<<4416, 256, 0, stream>>>(x, W_in, W_out, W_x, A_log,
                                        x_bf, WinT, WoutT, WxT, negA);
  // 2. x @ W_in -> xi (f32) | res_bf (bf16), 64x128 tile, 768 blocks
  gemm_bf16<2, 4, true><<<dim3(NXR / 128, MROWS / 64), 256, 0, stream>>>(
      x_bf, WinT, xi, res_bf, MROWS, NXR, DM);
  // 3. conv + bias + silu -> u_bf
  conv_silu_kernel<<<(MROWS * DI + 255) / 256, 256, 0, stream>>>(
      xi, conv_w, conv_b, u_bf);
  // 4. u @ W_x -> xdbl (MFMA)
  xdbl_mfma<<<MROWS / 16, 256, 0, stream>>>(u_bf, WxT, xdbl);
  // 5. delta
  delta_kernel<<<dim3(DI / 256, MROWS / DMP), 256, 0, stream>>>(xdbl, W_dt, b_dt, delta);
  // 6. chunked scan (NCHUNK=128, n-major state)
  scan_ph1<<<dim3(DI / SCB, NCHUNK, NBATCH), SCB, 0, stream>>>(
      delta, xdbl, u_bf, negA, Aprod, Hend);
  scan_ph2<<<(NBATCH * DI * NSTATE) / 256, 256, 0, stream>>>(Aprod, Hend);
  scan_ph3<<<dim3(DI / SCB, NCHUNK, NBATCH), SCB, 0, stream>>>(
      delta, xdbl, u_bf, res_bf, negA, Dp, Hend, yg);
  // 7. yg @ W_out -> out
  gemm_bf16<2, 2, false><<<dim3(DM / 64, MROWS / 64), 256, 0, stream>>>(
      yg, WoutT, out, nullptr, MROWS, DM, DI);
}